// Round 6
// baseline (1993.327 us; speedup 1.0000x reference)
//
#include <hip/hip_runtime.h>
#include <cmath>

// RecurrentGCN: GATv2Conv -> GConvGRU(1 step, H0=0) -> per-node MLP.
// Algebraic simplifications (verified against reference):
//  * H0=0  => cheb(H,...)=bias only; R unused (R*H=0); H_new=(1-Z)*Ht
//  * Z = sigmoid(cheb(h,W[0],b[0]) + b[1]);  Ht = tanh(cheb(h,W[4],b[4]) + b[5])
//  * both chebs share Tx0..Tx3 (3 sparse matvecs total)
//  * ea_mean@We = (sum_e ea@We)/cnt  (linearity) -> accumulate em per edge via
//    atomics; the ea array is NEVER re-gathered after the edge pass.
//  * MLPAggregation: out[k>0] = relu(H[k-1]@W1[:16]+b1)@W2+b2 ; out[0] from H=0
// R2 profile: CSR scatter of 3 arrays had ~10x write amplification (197MB
// writes, 223us). This version: single packed int2 {src,alpha} scatter (1 line
// per edge instead of 3) + emsum atomics instead of ea re-gather in k_gat.

constexpr int N = 50000;
constexpr int E = 1600000;

// ---------------- xl = x@Wl+bl, xr = x@Wr+br ----------------
__global__ __launch_bounds__(256)
void k_node_transform(const float* __restrict__ x,
                      const float* __restrict__ Wl, const float* __restrict__ bl,
                      const float* __restrict__ Wr, const float* __restrict__ br,
                      float* __restrict__ xl, float* __restrict__ xr) {
    __shared__ float sWl[128 * 16];
    __shared__ float sWr[128 * 16];
    int t = threadIdx.x;
    for (int i = t; i < 2048; i += 256) { sWl[i] = Wl[i]; sWr[i] = Wr[i]; }
    __syncthreads();
    int f = t & 15, nl = t >> 4;
    int n = blockIdx.x * 16 + nl;            // grid = N/16 exact (3125)
    const float4* xv = reinterpret_cast<const float4*>(x + (size_t)n * 128);
    float aL = bl[f], aR = br[f];
#pragma unroll 8
    for (int k4 = 0; k4 < 32; ++k4) {
        float4 v = xv[k4];
        int k = k4 * 4;
        aL += v.x * sWl[(k + 0) * 16 + f]; aR += v.x * sWr[(k + 0) * 16 + f];
        aL += v.y * sWl[(k + 1) * 16 + f]; aR += v.y * sWr[(k + 1) * 16 + f];
        aL += v.z * sWl[(k + 2) * 16 + f]; aR += v.z * sWr[(k + 2) * 16 + f];
        aL += v.w * sWl[(k + 3) * 16 + f]; aR += v.w * sWr[(k + 3) * 16 + f];
    }
    xl[n * 16 + f] = aL;
    xr[n * 16 + f] = aR;
}

// ---------------- in-degree (all edges) + out-degree (non-self) ----------------
__global__ __launch_bounds__(256)
void k_hist(const int* __restrict__ ei, int* __restrict__ cnt_in, int* __restrict__ deg_out) {
    int e = blockIdx.x * 256 + threadIdx.x;  // grid = E/256 exact
    int s = ei[e], d = ei[E + e];
    atomicAdd(&cnt_in[d], 1);
    if (s != d) atomicAdd(&deg_out[s], 1);
}

// ---------------- exclusive scan of cnt_in -> rowptr (single block) ----------------
// chunk=52 (mult of 4); lo always mult of 4; all int4 loads full.
__global__ __launch_bounds__(1024)
void k_scan(const int* __restrict__ cnt, int* __restrict__ rowptr, int n) {
    __shared__ int ssum[1024];
    int t = threadIdx.x;
    const int chunk = 52;
    int lo = t * chunk;
    int hi = lo + chunk; if (hi > n) hi = n; if (lo > n) lo = n;
    int s = 0;
    for (int i = lo; i + 3 < hi; i += 4) {
        int4 v = *reinterpret_cast<const int4*>(cnt + i);
        s += v.x + v.y + v.z + v.w;
    }
    ssum[t] = s;
    __syncthreads();
    for (int off = 1; off < 1024; off <<= 1) {
        int v = (t >= off) ? ssum[t - off] : 0;
        __syncthreads();
        ssum[t] += v;
        __syncthreads();
    }
    int prefix = (t == 0) ? 0 : ssum[t - 1];
    for (int i = lo; i < hi; ++i) { rowptr[i] = prefix; prefix += cnt[i]; }
    if (t == 0) rowptr[n] = ssum[1023];
}

// ---------------- per-edge alpha + packed CSR placement + emsum atomics --------
__global__ __launch_bounds__(256)
void k_edge_alpha(const int* __restrict__ ei, const float* __restrict__ ea,
                  const float* __restrict__ xl, const float* __restrict__ xr,
                  const float* __restrict__ We, const float* __restrict__ att,
                  const int* __restrict__ rowptr, int* __restrict__ ctr,
                  int2* __restrict__ sedge, float* __restrict__ emsum) {
    __shared__ float sWe[256];
    __shared__ float satt[16];
    int t = threadIdx.x;
    sWe[t] = We[t];
    if (t < 16) satt[t] = att[t];
    __syncthreads();
    int e = blockIdx.x * 256 + t;            // grid = E/256 exact (6250)
    int s = ei[e], d = ei[E + e];
    const float4* ea4 = reinterpret_cast<const float4*>(ea + (size_t)e * 16);
    float a[16];
#pragma unroll
    for (int j = 0; j < 4; ++j) {
        float4 v = ea4[j];
        a[4 * j] = v.x; a[4 * j + 1] = v.y; a[4 * j + 2] = v.z; a[4 * j + 3] = v.w;
    }
    const float4* xl4 = reinterpret_cast<const float4*>(xl + (size_t)s * 16);
    const float4* xr4 = reinterpret_cast<const float4*>(xr + (size_t)d * 16);
    float base[16];
#pragma unroll
    for (int j = 0; j < 4; ++j) {
        float4 L = xl4[j], R = xr4[j];
        base[4 * j]     = L.x + R.x; base[4 * j + 1] = L.y + R.y;
        base[4 * j + 2] = L.z + R.z; base[4 * j + 3] = L.w + R.w;
    }
    float em[16];
    float alpha = 0.f;
#pragma unroll
    for (int f = 0; f < 16; ++f) {
        float e2 = 0.f;
#pragma unroll
        for (int j = 0; j < 16; ++j) e2 += a[j] * sWe[j * 16 + f];
        em[f] = e2;
        float m = base[f] + e2;
        m = m > 0.f ? m : 0.2f * m;          // leaky_relu 0.2
        alpha += m * satt[f];
    }
    int p = rowptr[d] + atomicAdd(&ctr[d], 1);
    sedge[p] = make_int2(s, __float_as_int(alpha));
    float* es = emsum + (size_t)d * 16;
#pragma unroll
    for (int f = 0; f < 16; ++f) atomicAdd(&es[f], em[f]);
}

// ---- fused per-node GAT: amax -> self-loop alpha (from emsum) -> softmax sum
//      -> h, hs = dinv*h, acc init = h@W[·][0], dinv ----
__global__ __launch_bounds__(256)
void k_gat(const int* __restrict__ rowptr, const int2* __restrict__ sedge,
           const float* __restrict__ emsum, const float* __restrict__ xl,
           const float* __restrict__ xr, const int* __restrict__ deg_out,
           const float* __restrict__ att, const float* __restrict__ gat_bias,
           const float* __restrict__ Wz0, const float* __restrict__ Wh0,
           float* __restrict__ h, float* __restrict__ hs,
           float* __restrict__ accz, float* __restrict__ acch,
           float* __restrict__ dinv) {
    __shared__ float sWz[256], sWh[256];
    __shared__ float satt[16];
    __shared__ float sbuf[16][17];
    int t = threadIdx.x;
    sWz[t] = Wz0[t]; sWh[t] = Wh0[t];
    if (t < 16) satt[t] = att[t];
    __syncthreads();
    int f = t & 15, nl = t >> 4;
    int n = blockIdx.x * 16 + nl;            // grid = N/16 exact
    int lo = rowptr[n], hi = rowptr[n + 1];
    // pass 1: segment max, 16 lanes strided + shfl reduce (within 16-lane group)
    float amax = -3.0e38f;
    for (int i = lo + f; i < hi; i += 16)
        amax = fmaxf(amax, __int_as_float(sedge[i].y));
#pragma unroll
    for (int off = 1; off < 16; off <<= 1)
        amax = fmaxf(amax, __shfl_xor(amax, off, 64));
    // self-loop alpha from emsum (linearity: ea_mean@We = emsum/cnt)
    float cnt = (float)(hi - lo);
    float em = emsum[(size_t)n * 16 + f] / fmaxf(cnt, 1.f);
    float m = xl[n * 16 + f] + xr[n * 16 + f] + em;
    m = m > 0.f ? m : 0.2f * m;
    float c = m * satt[f];
#pragma unroll
    for (int off = 1; off < 16; off <<= 1) c += __shfl_xor(c, off, 64);
    float aloop = c;                          // identical across the 16 lanes
    amax = fmaxf(amax, aloop);
    // pass 2: softmax-weighted sum over incoming edges (sedge L2-warm)
    float num = 0.f, den = 0.f;
    for (int i = lo; i < hi; ++i) {
        int2 se = sedge[i];
        float ex = expf(__int_as_float(se.y) - amax);
        num += ex * xl[se.x * 16 + f];
        den += ex;
    }
    float exl = expf(aloop - amax);
    num += exl * xl[n * 16 + f];
    den += exl;
    float hv = num / (den + 1e-16f) + gat_bias[f];
    float dg = (float)deg_out[n];
    float di = dg > 0.f ? rsqrtf(dg) : 0.f;
    h[n * 16 + f] = hv;
    hs[n * 16 + f] = di * hv;                 // pre-scaled for cheb matvec
    if (f == 0) dinv[n] = di;
    __syncthreads();                          // reuse sbuf
    sbuf[nl][f] = hv;
    __syncthreads();
    float az = 0.f, ah = 0.f;
#pragma unroll
    for (int j = 0; j < 16; ++j) {
        float v = sbuf[nl][j];
        az += v * sWz[j * 16 + f];
        ah += v * sWh[j * 16 + f];
    }
    accz[n * 16 + f] = az;
    acch[n * 16 + f] = ah;
}

// ---- fused Cheb step: mv[n] = -dinv[n]*sum_{s!=n} Tins[s];
//      tv = mode ? 2*mv - Tprev : mv; optional stores; acc += tv@W[k] ----
__global__ __launch_bounds__(256)
void k_mvcomb(const int* __restrict__ rowptr, const int2* __restrict__ sedge,
              const float* __restrict__ dinv, const float* __restrict__ Tins,
              const float* __restrict__ Tprev, float* __restrict__ Tstore,
              float* __restrict__ Tscale_store,
              const float* __restrict__ Wzk, const float* __restrict__ Whk,
              float* __restrict__ accz, float* __restrict__ acch, int mode) {
    __shared__ float sWz[256], sWh[256];
    __shared__ float st[16][17];
    int t = threadIdx.x;
    sWz[t] = Wzk[t]; sWh[t] = Whk[t];
    int f = t & 15, nl = t >> 4;
    int n = blockIdx.x * 16 + nl;            // grid = N/16 exact
    int lo = rowptr[n], hi = rowptr[n + 1];
    float acc = 0.f;
    for (int i = lo; i < hi; ++i) {
        int s = sedge[i].x;
        if (s != n) acc += Tins[s * 16 + f]; // Tins already dinv-scaled
    }
    float di = dinv[n];
    float tv = -di * acc;
    if (mode) tv = 2.f * tv - Tprev[n * 16 + f];
    if (Tstore)       Tstore[n * 16 + f] = tv;
    if (Tscale_store) Tscale_store[n * 16 + f] = di * tv;
    st[nl][f] = tv;
    __syncthreads();
    float az = accz[n * 16 + f], ah = acch[n * 16 + f];
#pragma unroll
    for (int j = 0; j < 16; ++j) {
        float v = st[nl][j];
        az += v * sWz[j * 16 + f];
        ah += v * sWh[j * 16 + f];
    }
    accz[n * 16 + f] = az;
    acch[n * 16 + f] = ah;
}

// ---- last Cheb step fused with GRU combine + per-node MLP + out row 0 ----
__global__ __launch_bounds__(256)
void k_mvfinal(const int* __restrict__ rowptr, const int2* __restrict__ sedge,
               const float* __restrict__ dinv, const float* __restrict__ Tins,
               const float* __restrict__ Tprev,
               const float* __restrict__ Wzk, const float* __restrict__ Whk,
               const float* __restrict__ accz, const float* __restrict__ acch,
               const float* __restrict__ cheb_b,
               const float* __restrict__ W1, const float* __restrict__ b1,
               const float* __restrict__ W2, const float* __restrict__ b2,
               float* __restrict__ out) {
    __shared__ float sWz[256], sWh[256];
    __shared__ float st[16][17];
    int t = threadIdx.x;
    sWz[t] = Wzk[t]; sWh[t] = Whk[t];
    int f = t & 15, nl = t >> 4;
    int n = blockIdx.x * 16 + nl;            // grid = N/16 exact
    int lo = rowptr[n], hi = rowptr[n + 1];
    float acc = 0.f;
    for (int i = lo; i < hi; ++i) {
        int s = sedge[i].x;
        if (s != n) acc += Tins[s * 16 + f];
    }
    float tv = -dinv[n] * acc;
    tv = 2.f * tv - Tprev[n * 16 + f];        // T3 = 2 L T2 - T1
    st[nl][f] = tv;
    __syncthreads();
    float az = accz[n * 16 + f], ah = acch[n * 16 + f];
#pragma unroll
    for (int j = 0; j < 16; ++j) {
        float v = st[nl][j];
        az += v * sWz[j * 16 + f];
        ah += v * sWh[j * 16 + f];
    }
    // GRU (H0=0): Z = sigmoid(az + b[0] + b[1]); Ht = tanh(ah + b[4] + b[5])
    float z  = 1.f / (1.f + expf(-(az + cheb_b[f] + cheb_b[16 + f])));
    float ht = tanhf(ah + cheb_b[64 + f] + cheb_b[80 + f]);
    float H = (1.f - z) * ht;
    __syncthreads();                          // reuse st
    st[nl][f] = H;
    __syncthreads();
    float hid[4];
#pragma unroll
    for (int cc = 0; cc < 4; ++cc) {
        float v = b1[cc];
#pragma unroll
        for (int j = 0; j < 16; ++j) v += st[nl][j] * W1[j * 4 + cc];
        hid[cc] = fmaxf(v, 0.f);
    }
    if (f < 8) {
        float v = b2[f];
#pragma unroll
        for (int cc = 0; cc < 4; ++cc) v += hid[cc] * W2[cc * 8 + f];
        out[(size_t)(n + 1) * 8 + f] = v;
    }
    if (blockIdx.x == 0 && t == 0) {          // segment 0 is empty -> H = 0
        float h0[4];
#pragma unroll
        for (int cc = 0; cc < 4; ++cc) h0[cc] = fmaxf(b1[cc], 0.f);
#pragma unroll
        for (int o = 0; o < 8; ++o) {
            float v = b2[o];
#pragma unroll
            for (int cc = 0; cc < 4; ++cc) v += h0[cc] * W2[cc * 8 + o];
            out[o] = v;
        }
    }
}

extern "C" void kernel_launch(void* const* d_in, const int* in_sizes, int n_in,
                              void* d_out, int out_size, void* d_ws, size_t ws_size,
                              hipStream_t stream) {
    const float* x    = (const float*)d_in[0];
    const int*   ei   = (const int*)d_in[1];
    const float* ea   = (const float*)d_in[2];
    const float* Wl   = (const float*)d_in[3];
    const float* bl   = (const float*)d_in[4];
    const float* Wr   = (const float*)d_in[5];
    const float* br   = (const float*)d_in[6];
    const float* We   = (const float*)d_in[7];
    const float* att  = (const float*)d_in[8];
    const float* gatb = (const float*)d_in[9];
    const float* chW  = (const float*)d_in[10];  // [6][4][16][16]
    const float* chb  = (const float*)d_in[11];  // [6][16]
    const float* W1   = (const float*)d_in[12];
    const float* b1   = (const float*)d_in[13];
    const float* W2   = (const float*)d_in[14];
    const float* b2   = (const float*)d_in[15];
    float* out = (float*)d_out;

    char* w = (char*)d_ws;
    size_t off = 0;
    auto alloc = [&](size_t elems) {
        off = (off + 15) & ~(size_t)15;       // keep float4 alignment
        void* p = w + off;
        off += elems * 4;
        return p;
    };
    // zeroed region: cnt_in / deg_out / ctr / emsum contiguous (19N ints/floats)
    int*   cnt_in  = (int*)alloc(N);
    int*   deg_out = (int*)alloc(N);
    int*   ctr     = (int*)alloc(N);
    float* emsum   = (float*)alloc(16 * N);
    int*   rowptr  = (int*)alloc(N + 2);
    float* xl      = (float*)alloc(16 * N);
    float* xr      = (float*)alloc(16 * N);
    int2*  sedge   = (int2*)alloc(2 * (size_t)E);  // {src, alpha} packed
    float* dinv    = (float*)alloc(N);
    float* h       = (float*)alloc(16 * N);
    float* hs      = (float*)alloc(16 * N);   // dinv-scaled h
    float* accz    = (float*)alloc(16 * N);
    float* acch    = (float*)alloc(16 * N);
    float* T1      = (float*)alloc(16 * N);   // unscaled T1 (Tprev for step 3)
    float* Tsa     = (float*)alloc(16 * N);   // scaled current
    float* Tsb     = (float*)alloc(16 * N);
    (void)ws_size; (void)in_sizes; (void)n_in; (void)out_size;

    hipMemsetAsync(cnt_in, 0, (size_t)19 * N * sizeof(int), stream);

    k_node_transform<<<N / 16, 256, 0, stream>>>(x, Wl, bl, Wr, br, xl, xr);
    k_hist<<<E / 256, 256, 0, stream>>>(ei, cnt_in, deg_out);
    k_scan<<<1, 1024, 0, stream>>>(cnt_in, rowptr, N);
    k_edge_alpha<<<E / 256, 256, 0, stream>>>(ei, ea, xl, xr, We, att, rowptr, ctr,
                                              sedge, emsum);
    // cheb_W block k of cheb index i is at (i*4+k)*256 ; i=0 -> z path, i=4 -> h path
    k_gat<<<N / 16, 256, 0, stream>>>(rowptr, sedge, emsum, xl, xr, deg_out, att, gatb,
                                      chW + 0 * 256, chW + 16 * 256,
                                      h, hs, accz, acch, dinv);
    // T1 = L h            ; acc += T1@W[1]   (store T1 unscaled + scaled)
    k_mvcomb<<<N / 16, 256, 0, stream>>>(rowptr, sedge, dinv, hs, (const float*)nullptr,
                                         T1, Tsa, chW + 1 * 256, chW + 17 * 256,
                                         accz, acch, 0);
    // T2 = 2 L T1 - h     ; acc += T2@W[2]   (store scaled only)
    k_mvcomb<<<N / 16, 256, 0, stream>>>(rowptr, sedge, dinv, Tsa, h,
                                         (float*)nullptr, Tsb, chW + 2 * 256, chW + 18 * 256,
                                         accz, acch, 1);
    // T3 = 2 L T2 - T1 fused with GRU + MLP + out
    k_mvfinal<<<N / 16, 256, 0, stream>>>(rowptr, sedge, dinv, Tsb, T1,
                                          chW + 3 * 256, chW + 19 * 256,
                                          accz, acch, chb, W1, b1, W2, b2, out);
}

// Round 8
// 794.639 us; speedup vs baseline: 2.5085x; 2.5085x over previous
//
#include <hip/hip_runtime.h>
#include <cmath>

// RecurrentGCN: GATv2Conv -> GConvGRU(1 step, H0=0) -> per-node MLP.
// Algebraic simplifications (verified against reference):
//  * H0=0  => cheb(H,...)=bias only; R unused (R*H=0); H_new=(1-Z)*Ht
//  * Z = sigmoid(cheb(h,W[0],b[0]) + b[1]);  Ht = tanh(cheb(h,W[4],b[4]) + b[5])
//  * both chebs share Tx0..Tx3 (3 sparse matvecs total)
//  * MLPAggregation: out[k>0] = relu(H[k-1]@W1[:16]+b1)@W2+b2 ; out[0] from H=0
// R6 post-mortem: emsum ATOMICS were a 6x regression (899MB write traffic,
// 25.6M float RMWs across non-coherent XCD L2s). R2: 3-array scatter = 197MB.
// This version: edge pass is PLACEMENT ONLY (one 8B int2{src,eid} scatter =
// minimum possible); ALL alpha/em math moves into k_gat which gathers ea[eid]
// once (read-only random gather, no RFO/atomics) and runs ONLINE softmax
// (running-max rescale) in a single edge-parallel pass per segment.

constexpr int N = 50000;
constexpr int E = 1600000;

// ---------------- xl = x@Wl+bl, xr = x@Wr+br ----------------
__global__ __launch_bounds__(256)
void k_node_transform(const float* __restrict__ x,
                      const float* __restrict__ Wl, const float* __restrict__ bl,
                      const float* __restrict__ Wr, const float* __restrict__ br,
                      float* __restrict__ xl, float* __restrict__ xr) {
    __shared__ float sWl[128 * 16];
    __shared__ float sWr[128 * 16];
    int t = threadIdx.x;
    for (int i = t; i < 2048; i += 256) { sWl[i] = Wl[i]; sWr[i] = Wr[i]; }
    __syncthreads();
    int f = t & 15, nl = t >> 4;
    int n = blockIdx.x * 16 + nl;            // grid = N/16 exact (3125)
    const float4* xv = reinterpret_cast<const float4*>(x + (size_t)n * 128);
    float aL = bl[f], aR = br[f];
#pragma unroll 8
    for (int k4 = 0; k4 < 32; ++k4) {
        float4 v = xv[k4];
        int k = k4 * 4;
        aL += v.x * sWl[(k + 0) * 16 + f]; aR += v.x * sWr[(k + 0) * 16 + f];
        aL += v.y * sWl[(k + 1) * 16 + f]; aR += v.y * sWr[(k + 1) * 16 + f];
        aL += v.z * sWl[(k + 2) * 16 + f]; aR += v.z * sWr[(k + 2) * 16 + f];
        aL += v.w * sWl[(k + 3) * 16 + f]; aR += v.w * sWr[(k + 3) * 16 + f];
    }
    xl[n * 16 + f] = aL;
    xr[n * 16 + f] = aR;
}

// ---------------- in-degree (all edges) + out-degree (non-self) ----------------
__global__ __launch_bounds__(256)
void k_hist(const int* __restrict__ ei, int* __restrict__ cnt_in, int* __restrict__ deg_out) {
    int e = blockIdx.x * 256 + threadIdx.x;  // grid = E/256 exact
    int s = ei[e], d = ei[E + e];
    atomicAdd(&cnt_in[d], 1);
    if (s != d) atomicAdd(&deg_out[s], 1);
}

// ---------------- exclusive scan of cnt_in -> rowptr (single block) ----------------
// chunk=52 (mult of 4); lo always mult of 4; all int4 loads full.
__global__ __launch_bounds__(1024)
void k_scan(const int* __restrict__ cnt, int* __restrict__ rowptr, int n) {
    __shared__ int ssum[1024];
    int t = threadIdx.x;
    const int chunk = 52;
    int lo = t * chunk;
    int hi = lo + chunk; if (hi > n) hi = n; if (lo > n) lo = n;
    int s = 0;
    for (int i = lo; i + 3 < hi; i += 4) {
        int4 v = *reinterpret_cast<const int4*>(cnt + i);
        s += v.x + v.y + v.z + v.w;
    }
    ssum[t] = s;
    __syncthreads();
    for (int off = 1; off < 1024; off <<= 1) {
        int v = (t >= off) ? ssum[t - off] : 0;
        __syncthreads();
        ssum[t] += v;
        __syncthreads();
    }
    int prefix = (t == 0) ? 0 : ssum[t - 1];
    for (int i = lo; i < hi; ++i) { rowptr[i] = prefix; prefix += cnt[i]; }
    if (t == 0) rowptr[n] = ssum[1023];
}

// ---------------- CSR placement ONLY: one packed 8B scatter per edge ----------
__global__ __launch_bounds__(256)
void k_edge_place(const int* __restrict__ ei, const int* __restrict__ rowptr,
                  int* __restrict__ ctr, int2* __restrict__ sedge) {
    int e = blockIdx.x * 256 + threadIdx.x;  // grid = E/256 exact
    int s = ei[e], d = ei[E + e];
    int p = rowptr[d] + atomicAdd(&ctr[d], 1);
    sedge[p] = make_int2(s, e);              // {src, eid}
}

// ---- fused per-node GAT, single pass, edge-parallel lanes, online softmax.
//      Lane f of each 16-lane group owns edges lo+f, lo+f+16, ... of node n.
//      Per edge: gather ea[eid] (64B) + xl[src] (64B); em = ea@We (256 FMA);
//      alpha = leaky(xl_s+xr_d+em)@att; online num/den with running max.
//      Node-level: LDS transpose-reduce -> feature-parallel epilogue
//      (self-loop via emsum linearity, h, hs=dinv*h, acc init). ----
__global__ __launch_bounds__(256)
void k_gat(const int* __restrict__ rowptr, const int2* __restrict__ sedge,
           const float* __restrict__ ea, const float* __restrict__ xl,
           const float* __restrict__ xr, const int* __restrict__ deg_out,
           const float* __restrict__ We, const float* __restrict__ att,
           const float* __restrict__ gat_bias,
           const float* __restrict__ Wz0, const float* __restrict__ Wh0,
           float* __restrict__ h, float* __restrict__ hs,
           float* __restrict__ accz, float* __restrict__ acch,
           float* __restrict__ dinv) {
    __shared__ float sWe[256], sWz[256], sWh[256];
    __shared__ float satt[16];
    __shared__ float strans[16][16][17];     // [node][lane][feat(+pad)]
    __shared__ float sbuf[16][17];
    int t = threadIdx.x;
    sWe[t] = We[t]; sWz[t] = Wz0[t]; sWh[t] = Wh0[t];
    if (t < 16) satt[t] = att[t];
    __syncthreads();
    int f = t & 15, nl = t >> 4;
    int n = blockIdx.x * 16 + nl;            // grid = N/16 exact
    int lo = rowptr[n], hi = rowptr[n + 1];
    // node-constant xr row (broadcast load, all constant-indexed)
    float xrn[16];
    {
        const float4* xr4 = reinterpret_cast<const float4*>(xr + (size_t)n * 16);
#pragma unroll
        for (int j = 0; j < 4; ++j) {
            float4 v = xr4[j];
            xrn[4*j] = v.x; xrn[4*j+1] = v.y; xrn[4*j+2] = v.z; xrn[4*j+3] = v.w;
        }
    }
    float m_l = -3.0e38f, den_l = 0.f;
    float num_l[16], emacc[16];
#pragma unroll
    for (int j = 0; j < 16; ++j) { num_l[j] = 0.f; emacc[j] = 0.f; }
    for (int i = lo + f; i < hi; i += 16) {
        int2 se = sedge[i];                  // coalesced within group
        const float4* ea4 = reinterpret_cast<const float4*>(ea + (size_t)se.y * 16);
        const float4* xl4 = reinterpret_cast<const float4*>(xl + (size_t)se.x * 16);
        float a[16], xs[16];
#pragma unroll
        for (int j = 0; j < 4; ++j) {
            float4 v = ea4[j]; a[4*j] = v.x; a[4*j+1] = v.y; a[4*j+2] = v.z; a[4*j+3] = v.w;
            float4 u = xl4[j]; xs[4*j] = u.x; xs[4*j+1] = u.y; xs[4*j+2] = u.z; xs[4*j+3] = u.w;
        }
        float alpha = 0.f;
#pragma unroll
        for (int f2 = 0; f2 < 16; ++f2) {
            float em = 0.f;
#pragma unroll
            for (int j = 0; j < 16; ++j) em += a[j] * sWe[j * 16 + f2];
            emacc[f2] += em;
            float m = xs[f2] + xrn[f2] + em;
            m = m > 0.f ? m : 0.2f * m;      // leaky_relu 0.2
            alpha += m * satt[f2];
        }
        float ex;
        if (alpha > m_l) {                   // online-softmax rescale
            float sc = expf(m_l - alpha);    // first edge: exp(-3e38-a) -> 0
            den_l *= sc;
#pragma unroll
            for (int j = 0; j < 16; ++j) num_l[j] *= sc;
            m_l = alpha; ex = 1.f;
        } else {
            ex = expf(alpha - m_l);
        }
        den_l += ex;
#pragma unroll
        for (int j = 0; j < 16; ++j) num_l[j] += ex * xs[j];
    }
    // combine 16 lanes: global max, rescale, reduce
    float M = m_l;
#pragma unroll
    for (int off = 1; off < 16; off <<= 1) M = fmaxf(M, __shfl_xor(M, off, 64));
    float s_l = expf(m_l - M);               // empty lane: exp(-3e38-M)=0 (or 1*den0=0)
    float den = den_l * s_l;
#pragma unroll
    for (int off = 1; off < 16; off <<= 1) den += __shfl_xor(den, off, 64);
    // transpose-reduce num (lane-major -> feature-major)
#pragma unroll
    for (int j = 0; j < 16; ++j) strans[nl][f][j] = num_l[j] * s_l;
    __syncthreads();
    float num_f = 0.f;
#pragma unroll
    for (int j = 0; j < 16; ++j) num_f += strans[nl][j][f];
    __syncthreads();
#pragma unroll
    for (int j = 0; j < 16; ++j) strans[nl][f][j] = emacc[j];
    __syncthreads();
    float emsum_f = 0.f;
#pragma unroll
    for (int j = 0; j < 16; ++j) emsum_f += strans[nl][j][f];
    // self-loop alpha via linearity: ea_mean@We = emsum/cnt
    float cntf = (float)(hi - lo);
    float xlf = xl[n * 16 + f];
    float xrf = xr[n * 16 + f];              // scalar load (avoid xrn[f] dyn-index)
    float m0 = xlf + xrf + emsum_f / fmaxf(cntf, 1.f);
    m0 = m0 > 0.f ? m0 : 0.2f * m0;
    float c = m0 * satt[f];
#pragma unroll
    for (int off = 1; off < 16; off <<= 1) c += __shfl_xor(c, off, 64);
    float aloop = c;
    float Mf = fmaxf(M, aloop);
    float sc2 = expf(M - Mf);                // no-edge node: exp(-3e38-aloop)=0
    float exl = expf(aloop - Mf);
    num_f = num_f * sc2 + exl * xlf;
    float dent = den * sc2 + exl;
    float hv = num_f / (dent + 1e-16f) + gat_bias[f];
    float dg = (float)deg_out[n];
    float di = dg > 0.f ? rsqrtf(dg) : 0.f;
    h[n * 16 + f] = hv;
    hs[n * 16 + f] = di * hv;                // pre-scaled for cheb matvec
    if (f == 0) dinv[n] = di;
    // acc init = h @ W[.][0]
    sbuf[nl][f] = hv;
    __syncthreads();
    float az = 0.f, ah = 0.f;
#pragma unroll
    for (int j = 0; j < 16; ++j) {
        float v = sbuf[nl][j];
        az += v * sWz[j * 16 + f];
        ah += v * sWh[j * 16 + f];
    }
    accz[n * 16 + f] = az;
    acch[n * 16 + f] = ah;
}

// ---- fused Cheb step: mv[n] = -dinv[n]*sum_{s!=n} Tins[s];
//      tv = mode ? 2*mv - Tprev : mv; optional stores; acc += tv@W[k] ----
__global__ __launch_bounds__(256)
void k_mvcomb(const int* __restrict__ rowptr, const int2* __restrict__ sedge,
              const float* __restrict__ dinv, const float* __restrict__ Tins,
              const float* __restrict__ Tprev, float* __restrict__ Tstore,
              float* __restrict__ Tscale_store,
              const float* __restrict__ Wzk, const float* __restrict__ Whk,
              float* __restrict__ accz, float* __restrict__ acch, int mode) {
    __shared__ float sWz[256], sWh[256];
    __shared__ float st[16][17];
    int t = threadIdx.x;
    sWz[t] = Wzk[t]; sWh[t] = Whk[t];
    int f = t & 15, nl = t >> 4;
    int n = blockIdx.x * 16 + nl;            // grid = N/16 exact
    int lo = rowptr[n], hi = rowptr[n + 1];
    float acc = 0.f;
    for (int i = lo; i < hi; ++i) {
        int s = sedge[i].x;
        if (s != n) acc += Tins[s * 16 + f]; // Tins already dinv-scaled
    }
    float di = dinv[n];
    float tv = -di * acc;
    if (mode) tv = 2.f * tv - Tprev[n * 16 + f];
    if (Tstore)       Tstore[n * 16 + f] = tv;
    if (Tscale_store) Tscale_store[n * 16 + f] = di * tv;
    st[nl][f] = tv;
    __syncthreads();
    float az = accz[n * 16 + f], ah = acch[n * 16 + f];
#pragma unroll
    for (int j = 0; j < 16; ++j) {
        float v = st[nl][j];
        az += v * sWz[j * 16 + f];
        ah += v * sWh[j * 16 + f];
    }
    accz[n * 16 + f] = az;
    acch[n * 16 + f] = ah;
}

// ---- last Cheb step fused with GRU combine + per-node MLP + out row 0 ----
__global__ __launch_bounds__(256)
void k_mvfinal(const int* __restrict__ rowptr, const int2* __restrict__ sedge,
               const float* __restrict__ dinv, const float* __restrict__ Tins,
               const float* __restrict__ Tprev,
               const float* __restrict__ Wzk, const float* __restrict__ Whk,
               const float* __restrict__ accz, const float* __restrict__ acch,
               const float* __restrict__ cheb_b,
               const float* __restrict__ W1, const float* __restrict__ b1,
               const float* __restrict__ W2, const float* __restrict__ b2,
               float* __restrict__ out) {
    __shared__ float sWz[256], sWh[256];
    __shared__ float st[16][17];
    int t = threadIdx.x;
    sWz[t] = Wzk[t]; sWh[t] = Whk[t];
    int f = t & 15, nl = t >> 4;
    int n = blockIdx.x * 16 + nl;            // grid = N/16 exact
    int lo = rowptr[n], hi = rowptr[n + 1];
    float acc = 0.f;
    for (int i = lo; i < hi; ++i) {
        int s = sedge[i].x;
        if (s != n) acc += Tins[s * 16 + f];
    }
    float tv = -dinv[n] * acc;
    tv = 2.f * tv - Tprev[n * 16 + f];        // T3 = 2 L T2 - T1
    st[nl][f] = tv;
    __syncthreads();
    float az = accz[n * 16 + f], ah = acch[n * 16 + f];
#pragma unroll
    for (int j = 0; j < 16; ++j) {
        float v = st[nl][j];
        az += v * sWz[j * 16 + f];
        ah += v * sWh[j * 16 + f];
    }
    // GRU (H0=0): Z = sigmoid(az + b[0] + b[1]); Ht = tanh(ah + b[4] + b[5])
    float z  = 1.f / (1.f + expf(-(az + cheb_b[f] + cheb_b[16 + f])));
    float ht = tanhf(ah + cheb_b[64 + f] + cheb_b[80 + f]);
    float H = (1.f - z) * ht;
    __syncthreads();                          // reuse st
    st[nl][f] = H;
    __syncthreads();
    float hid[4];
#pragma unroll
    for (int cc = 0; cc < 4; ++cc) {
        float v = b1[cc];
#pragma unroll
        for (int j = 0; j < 16; ++j) v += st[nl][j] * W1[j * 4 + cc];
        hid[cc] = fmaxf(v, 0.f);
    }
    if (f < 8) {
        float v = b2[f];
#pragma unroll
        for (int cc = 0; cc < 4; ++cc) v += hid[cc] * W2[cc * 8 + f];
        out[(size_t)(n + 1) * 8 + f] = v;
    }
    if (blockIdx.x == 0 && t == 0) {          // segment 0 is empty -> H = 0
        float h0[4];
#pragma unroll
        for (int cc = 0; cc < 4; ++cc) h0[cc] = fmaxf(b1[cc], 0.f);
#pragma unroll
        for (int o = 0; o < 8; ++o) {
            float v = b2[o];
#pragma unroll
            for (int cc = 0; cc < 4; ++cc) v += h0[cc] * W2[cc * 8 + o];
            out[o] = v;
        }
    }
}

extern "C" void kernel_launch(void* const* d_in, const int* in_sizes, int n_in,
                              void* d_out, int out_size, void* d_ws, size_t ws_size,
                              hipStream_t stream) {
    const float* x    = (const float*)d_in[0];
    const int*   ei   = (const int*)d_in[1];
    const float* ea   = (const float*)d_in[2];
    const float* Wl   = (const float*)d_in[3];
    const float* bl   = (const float*)d_in[4];
    const float* Wr   = (const float*)d_in[5];
    const float* br   = (const float*)d_in[6];
    const float* We   = (const float*)d_in[7];
    const float* att  = (const float*)d_in[8];
    const float* gatb = (const float*)d_in[9];
    const float* chW  = (const float*)d_in[10];  // [6][4][16][16]
    const float* chb  = (const float*)d_in[11];  // [6][16]
    const float* W1   = (const float*)d_in[12];
    const float* b1   = (const float*)d_in[13];
    const float* W2   = (const float*)d_in[14];
    const float* b2   = (const float*)d_in[15];
    float* out = (float*)d_out;

    char* w = (char*)d_ws;
    size_t off = 0;
    auto alloc = [&](size_t elems) {
        off = (off + 15) & ~(size_t)15;       // keep float4/int2 alignment
        void* p = w + off;
        off += elems * 4;
        return p;
    };
    // zeroed region: cnt_in / deg_out / ctr contiguous (3N ints)
    int*   cnt_in  = (int*)alloc(N);
    int*   deg_out = (int*)alloc(N);
    int*   ctr     = (int*)alloc(N);
    int*   rowptr  = (int*)alloc(N + 2);
    float* xl      = (float*)alloc(16 * N);
    float* xr      = (float*)alloc(16 * N);
    int2*  sedge   = (int2*)alloc(2 * (size_t)E);  // {src, eid} packed
    float* dinv    = (float*)alloc(N);
    float* h       = (float*)alloc(16 * N);
    float* hs      = (float*)alloc(16 * N);   // dinv-scaled h
    float* accz    = (float*)alloc(16 * N);
    float* acch    = (float*)alloc(16 * N);
    float* T1      = (float*)alloc(16 * N);   // unscaled T1 (Tprev for step 3)
    float* Tsa     = (float*)alloc(16 * N);   // scaled current
    float* Tsb     = (float*)alloc(16 * N);
    (void)ws_size; (void)in_sizes; (void)n_in; (void)out_size;

    hipMemsetAsync(cnt_in, 0, (size_t)3 * N * sizeof(int), stream);

    k_node_transform<<<N / 16, 256, 0, stream>>>(x, Wl, bl, Wr, br, xl, xr);
    k_hist<<<E / 256, 256, 0, stream>>>(ei, cnt_in, deg_out);
    k_scan<<<1, 1024, 0, stream>>>(cnt_in, rowptr, N);
    k_edge_place<<<E / 256, 256, 0, stream>>>(ei, rowptr, ctr, sedge);
    // cheb_W block k of cheb index i is at (i*4+k)*256 ; i=0 -> z path, i=4 -> h path
    k_gat<<<N / 16, 256, 0, stream>>>(rowptr, sedge, ea, xl, xr, deg_out, We, att,
                                      gatb, chW + 0 * 256, chW + 16 * 256,
                                      h, hs, accz, acch, dinv);
    // T1 = L h            ; acc += T1@W[1]   (store T1 unscaled + scaled)
    k_mvcomb<<<N / 16, 256, 0, stream>>>(rowptr, sedge, dinv, hs, (const float*)nullptr,
                                         T1, Tsa, chW + 1 * 256, chW + 17 * 256,
                                         accz, acch, 0);
    // T2 = 2 L T1 - h     ; acc += T2@W[2]   (store scaled only)
    k_mvcomb<<<N / 16, 256, 0, stream>>>(rowptr, sedge, dinv, Tsa, h,
                                         (float*)nullptr, Tsb, chW + 2 * 256, chW + 18 * 256,
                                         accz, acch, 1);
    // T3 = 2 L T2 - T1 fused with GRU + MLP + out
    k_mvfinal<<<N / 16, 256, 0, stream>>>(rowptr, sedge, dinv, Tsb, T1,
                                          chW + 3 * 256, chW + 19 * 256,
                                          accz, acch, chb, W1, b1, W2, b2, out);
}